// Round 7
// baseline (463.370 us; speedup 1.0000x reference)
//
#include <hip/hip_runtime.h>
#include <hip/hip_bf16.h>

// B=2, S=1024, L=1024, DIM_Q=2048, H=16, K=128, D_C=512, D_CQ=1536, R=64

typedef __attribute__((ext_vector_type(8))) short short8;
typedef __attribute__((ext_vector_type(4))) float f32x4;

__device__ __forceinline__ unsigned short f2bs(float v){
  __hip_bfloat16 b = __float2bfloat16(v);
  return *reinterpret_cast<unsigned short*>(&b);
}
__device__ __forceinline__ void storeC(float* p, float v){ *p = v; }
__device__ __forceinline__ void storeC(unsigned short* p, float v){ *p = f2bs(v); }

// async global->LDS, 16B per lane.  LDS dest = wave-uniform base + lane*16.
__device__ __forceinline__ void gl_lds16(const void* g, void* l){
  __builtin_amdgcn_global_load_lds(
      (const __attribute__((address_space(1))) unsigned int*)g,
      (__attribute__((address_space(3))) unsigned int*)l, 16, 0, 0);
}

// ---------------------------------------------------------------------------
// prep_all: one launch for sin/cos tables + 3 fp32->bf16 converts.
__global__ __launch_bounds__(256) void prep_all(
    float* __restrict__ sinq, float* __restrict__ cosq,
    float* __restrict__ sink, float* __restrict__ cosk,
    const float* __restrict__ hidden, unsigned short* __restrict__ hiddenb,
    const float* __restrict__ Wq, unsigned short* __restrict__ Wqb,
    const float* __restrict__ wkckv, unsigned short* __restrict__ wkckvb)
{
  int blk = blockIdx.x;
  if (blk < 4096){
    int idx = blk*256 + threadIdx.x;
    if (idx < 1024*768){
      int s = idx / 768, j = idx % 768;
      float f = (float)s * powf(10000.f, (-2.f*j)/1536.f);
      float sv = sinf(f), cv = cosf(f);
      int base = s*1536 + 2*j;
      sinq[base] = sv; sinq[base+1] = sv;
      cosq[base] = cv; cosq[base+1] = cv;
    } else {
      int k = idx - 1024*768;
      int l = k / 256, j = k % 256;
      float f = (float)l * powf(10000.f, (-2.f*j)/512.f);
      float sv = sinf(f), cv = cosf(f);
      int base = l*512 + 2*j;
      sink[base] = sv; sink[base+1] = sv;
      cosk[base] = cv; cosk[base+1] = cv;
    }
    return;
  }
  const float* in; unsigned short* out; int i;
  if (blk < 8192){ in = hidden; out = hiddenb; i = (blk-4096)*256 + threadIdx.x; }
  else if (blk < 12288){ in = Wq; out = Wqb; i = (blk-8192)*256 + threadIdx.x; }
  else { in = wkckv; out = wkckvb; i = (blk-12288)*256 + threadIdx.x; }
  float4 v = *(const float4*)(in + (long)i*4);
  ushort4 u; u.x=f2bs(v.x); u.y=f2bs(v.y); u.z=f2bs(v.z); u.w=f2bs(v.w);
  *(ushort4*)(out + (long)i*4) = u;
}

__global__ __launch_bounds__(256) void cvt_bf16(
    const float* __restrict__ in, unsigned short* __restrict__ out, int n4)
{
  int i = blockIdx.x*256 + threadIdx.x;
  if (i < n4){
    float4 v = *(const float4*)(in + (long)i*4);
    ushort4 u; u.x=f2bs(v.x); u.y=f2bs(v.y); u.z=f2bs(v.z); u.w=f2bs(v.w);
    *(ushort4*)(out + (long)i*4) = u;
  }
}

// fp32 [R,Cn] -> bf16 [Cn,R] per batch (32x32 LDS tiles)
__global__ __launch_bounds__(256) void transpose_cvt(
    const float* __restrict__ in, unsigned short* __restrict__ out,
    int R, int Cn, long sIn, long sOut)
{
  __shared__ float tile[32][33];
  const float* ip = in + (long)blockIdx.z*sIn;
  unsigned short* op = out + (long)blockIdx.z*sOut;
  int c0 = blockIdx.x*32, r0 = blockIdx.y*32;
  int tr = threadIdx.x>>5, tc = threadIdx.x&31;
  #pragma unroll
  for (int i=0;i<4;i++)
    tile[tr+i*8][tc] = ip[(long)(r0+tr+i*8)*Cn + c0+tc];
  __syncthreads();
  #pragma unroll
  for (int i=0;i<4;i++)
    op[(long)(c0+tr+i*8)*R + r0+tc] = f2bs(tile[tc][tr+i*8]);
}

// ---------------------------------------------------------------------------
// bf16 MFMA GEMM (NT), double-buffered LDS.  C[m,n] = sum_k A[m,k]*B[n,k].
template<int BM,int BN,int WM,int WN,typename TC>
__global__ __launch_bounds__(256) void gemm_mfma(
    const unsigned short* __restrict__ A, const unsigned short* __restrict__ B,
    TC* __restrict__ C,
    int Kd, int lda, int ldb, int ldc, int Hb,
    long sAb, long sAh, long sBb, long sBh, long sCb, long sCh)
{
  constexpr int MF = WM/16, NF = WN/16;
  constexpr int WGM = BM/WM;
  constexpr int AOPS = (4*BM)/256;
  constexpr int BOPS = (4*BN)/256;

  const int z = blockIdx.z, bb = z/Hb, hh = z - bb*Hb;
  const unsigned short* Ap = A + bb*sAb + hh*sAh;
  const unsigned short* Bp = B + bb*sBb + hh*sBh;
  TC* Cp = C + bb*sCb + hh*sCh;
  const int m0 = blockIdx.x*BM, n0 = blockIdx.y*BN;
  const int t = threadIdx.x, w = t>>6, l = t&63;
  const int wm0 = (w % WGM)*WM, wn0 = (w / WGM)*WN;
  const int lq = l>>4, lm = l&15;

  __shared__ __align__(16) unsigned short As[2][4*BM*8];
  __shared__ __align__(16) unsigned short Bs[2][4*BN*8];

  f32x4 acc[MF][NF];
  #pragma unroll
  for (int mf=0; mf<MF; ++mf)
    #pragma unroll
    for (int nf=0; nf<NF; ++nf)
      acc[mf][nf] = f32x4{0.f,0.f,0.f,0.f};

  auto stage = [&](int buf, int k0){
    #pragma unroll
    for (int o = 0; o < AOPS; ++o){
      int g = o*256 + t;
      int row = g & (BM-1), kq = g / BM;
      gl_lds16(Ap + (long)(m0+row)*lda + k0 + kq*8, &As[buf][(o*256 + w*64)*8]);
    }
    #pragma unroll
    for (int o = 0; o < BOPS; ++o){
      int g = o*256 + t;
      int row = g & (BN-1), kq = g / BN;
      gl_lds16(Bp + (long)(n0+row)*ldb + k0 + kq*8, &Bs[buf][(o*256 + w*64)*8]);
    }
  };

  stage(0, 0);
  const int nIter = Kd >> 5;
  for (int it = 0; it < nIter; ++it){
    const int cur = it & 1;
    __syncthreads();
    if (it+1 < nIter) stage(cur^1, (it+1)*32);
    short8 af[MF], bfr[NF];
    #pragma unroll
    for (int mf=0; mf<MF; ++mf)
      af[mf] = *(const short8*)&As[cur][(lq*BM + wm0 + mf*16 + lm)*8];
    #pragma unroll
    for (int nf=0; nf<NF; ++nf)
      bfr[nf] = *(const short8*)&Bs[cur][(lq*BN + wn0 + nf*16 + lm)*8];
    #pragma unroll
    for (int mf=0; mf<MF; ++mf)
      #pragma unroll
      for (int nf=0; nf<NF; ++nf)
        acc[mf][nf] = __builtin_amdgcn_mfma_f32_16x16x32_bf16(
            af[mf], bfr[nf], acc[mf][nf], 0, 0, 0);
  }

  #pragma unroll
  for (int mf=0; mf<MF; ++mf){
    #pragma unroll
    for (int nf=0; nf<NF; ++nf){
      int row = m0 + wm0 + mf*16 + lq*4;
      int col = n0 + wn0 + nf*16 + lm;
      #pragma unroll
      for (int r=0; r<4; ++r)
        storeC(&Cp[(long)(row+r)*ldc + col], acc[mf][nf][r]);
    }
  }
}

// ---------------------------------------------------------------------------
// Step 3 + RoPE fused: q_big[b,s][h*1536+q] = RoPE(q_hk @ w_kc_q_T).
// Split-N tile: block covers cols [n0,n0+64) U [n0+768,n0+832) so both RoPE
// partners (q, q+768) live in the same thread's accs (acc[mf][p] / acc[mf][p+4]).
// Waves span full N (WM=32, WN=128).  K=128 (4 chunks), double-buffered.
__global__ __launch_bounds__(256) void gemm_rope(
    const unsigned short* __restrict__ A,   // q_hk [2048][2048]
    const unsigned short* __restrict__ Bt,  // wkcqT [16][1536][128]
    unsigned short* __restrict__ Cq,        // q_big [2048][24576]
    const float* __restrict__ sq, const float* __restrict__ cq)
{
  const int z = blockIdx.z, bb = z >> 4, hh = z & 15;
  const unsigned short* Ap = A + (long)bb*2097152 + hh*128;
  const unsigned short* Bp = Bt + (long)hh*196608;
  unsigned short* Cp = Cq + (long)bb*25165824 + hh*1536;
  const int m0 = blockIdx.x*128, n0 = blockIdx.y*64;
  const int t = threadIdx.x, w = t>>6, l = t&63;
  const int lq = l>>4, lm = l&15;

  __shared__ __align__(16) unsigned short As[2][4*128*8];
  __shared__ __align__(16) unsigned short Bs[2][4*128*8];

  f32x4 acc[2][8];
  #pragma unroll
  for (int mf=0; mf<2; ++mf)
    #pragma unroll
    for (int nf=0; nf<8; ++nf)
      acc[mf][nf] = f32x4{0.f,0.f,0.f,0.f};

  auto stage = [&](int buf, int k0){
    #pragma unroll
    for (int o = 0; o < 2; ++o){
      int g = o*256 + t;
      int row = g & 127, kq = g >> 7;
      gl_lds16(Ap + (long)(m0+row)*2048 + k0 + kq*8, &As[buf][(o*256 + w*64)*8]);
    }
    #pragma unroll
    for (int o = 0; o < 2; ++o){
      int g = o*256 + t;
      int row = g & 127, kq = g >> 7;
      int grow = (row < 64) ? (n0 + row) : (704 + n0 + row);  // low/high half
      gl_lds16(Bp + (long)grow*128 + k0 + kq*8, &Bs[buf][(o*256 + w*64)*8]);
    }
  };

  stage(0, 0);
  #pragma unroll
  for (int it = 0; it < 4; ++it){
    const int cur = it & 1;
    __syncthreads();
    if (it < 3) stage(cur^1, (it+1)*32);
    short8 af[2], bfr[8];
    #pragma unroll
    for (int mf=0; mf<2; ++mf)
      af[mf] = *(const short8*)&As[cur][(lq*128 + w*32 + mf*16 + lm)*8];
    #pragma unroll
    for (int nf=0; nf<8; ++nf)
      bfr[nf] = *(const short8*)&Bs[cur][(lq*128 + nf*16 + lm)*8];
    #pragma unroll
    for (int mf=0; mf<2; ++mf)
      #pragma unroll
      for (int nf=0; nf<8; ++nf)
        acc[mf][nf] = __builtin_amdgcn_mfma_f32_16x16x32_bf16(
            af[mf], bfr[nf], acc[mf][nf], 0, 0, 0);
  }

  // fused RoPE epilogue: pair p (cols q_lo=n0+p*16+lm) with p+4 (q_lo+768)
  #pragma unroll
  for (int mf=0; mf<2; ++mf){
    int rowb = m0 + w*32 + mf*16 + lq*4;
    #pragma unroll
    for (int p=0; p<4; ++p){
      int q_lo = n0 + p*16 + lm;
      #pragma unroll
      for (int r=0; r<4; ++r){
        int s = rowb + r;
        int tb = s*1536 + q_lo;
        float xl = acc[mf][p][r], xh = acc[mf][p+4][r];
        float y_lo = xl*cq[tb]     - xh*sq[tb];
        float y_hi = xh*cq[tb+768] + xl*sq[tb+768];
        Cp[(long)s*24576 + q_lo]       = f2bs(y_lo);
        Cp[(long)s*24576 + q_lo + 768] = f2bs(y_hi);
      }
    }
  }
}

// ---------------------------------------------------------------------------
// RoPE on kv_c -> kv_rb bf16.  [b,l,512]; pairs (d, d+256).
__global__ __launch_bounds__(256) void rope_k_kernel(
    const float* __restrict__ kc,
    const float* __restrict__ sk, const float* __restrict__ ck,
    unsigned short* __restrict__ kvrb)
{
  int idx = blockIdx.x*256 + threadIdx.x;
  int row = idx >> 8;
  int d = idx & 255;
  int l = row & 1023;
  long base = (long)row*512;
  float xl = kc[base+d], xh = kc[base+d+256];
  int tb = l*512 + d;
  kvrb[base+d]     = f2bs(xl*ck[tb]     - xh*sk[tb]);
  kvrb[base+d+256] = f2bs(xh*ck[tb+256] + xl*sk[tb+256]);
}

// ---------------------------------------------------------------------------
// MFMA flash attention, double-buffered K/V staging.
__global__ __launch_bounds__(256) void flash_mfma(
    const unsigned short* __restrict__ qr, const unsigned short* __restrict__ kr,
    const unsigned short* __restrict__ vt, unsigned short* __restrict__ ctx)
{
  const int b = blockIdx.z, h = blockIdx.y, s0 = blockIdx.x*64;
  const int t = threadIdx.x, w = t>>6, l = t&63;
  const int lq = l>>4, lm = l&15;

  __shared__ __align__(16) unsigned short Qs[8*64*8];
  __shared__ __align__(16) unsigned short Ks[2][8*64*8];
  __shared__ __align__(16) unsigned short Vts[2][8*128*8];
  __shared__ __align__(16) unsigned short Ps[64*72];

  const unsigned short* qbase = qr + ((long)(b*16+h)*1024 + s0)*64;
  const unsigned short* kbase = kr + (long)(b*16+h)*65536;
  const unsigned short* vbase = vt + (long)(b*16+h)*131072;

  auto stageKV = [&](int buf, int l0){
    #pragma unroll
    for (int o = 0; o < 2; ++o){
      int g = o*256 + t;
      int row = g & 63, kq = g >> 6;
      gl_lds16(kbase + (long)(l0+row)*64 + kq*8, &Ks[buf][(o*256 + w*64)*8]);
    }
    #pragma unroll
    for (int o = 0; o < 4; ++o){
      int g = o*256 + t;
      int row = g & 127, kq = g >> 7;
      gl_lds16(vbase + (long)row*1024 + l0 + kq*8, &Vts[buf][(o*256 + w*64)*8]);
    }
  };

  #pragma unroll
  for (int o = 0; o < 2; ++o){
    int g = o*256 + t;
    int row = g & 63, kq = g >> 6;
    gl_lds16(qbase + (long)row*64 + kq*8, &Qs[(o*256 + w*64)*8]);
  }
  stageKV(0, 0);
  __syncthreads();
  short8 aq[2];
  #pragma unroll
  for (int ks = 0; ks < 2; ++ks)
    aq[ks] = *(const short8*)&Qs[((ks*4+lq)*64 + w*16 + lm)*8];

  float m_run[4], l_run[4];
  #pragma unroll
  for (int r = 0; r < 4; ++r){ m_run[r] = -3e38f; l_run[r] = 0.f; }
  f32x4 acc_o[8];
  #pragma unroll
  for (int nf = 0; nf < 8; ++nf) acc_o[nf] = f32x4{0.f,0.f,0.f,0.f};

  for (int it = 0; it < 16; ++it){
    const int cur = it & 1;
    __syncthreads();
    if (it < 15) stageKV(cur^1, (it+1)*64);

    f32x4 acc_s[4];
    #pragma unroll
    for (int nf = 0; nf < 4; ++nf) acc_s[nf] = f32x4{0.f,0.f,0.f,0.f};
    #pragma unroll
    for (int ks = 0; ks < 2; ++ks)
      #pragma unroll
      for (int nf = 0; nf < 4; ++nf){
        short8 bf = *(const short8*)&Ks[cur][((ks*4+lq)*64 + nf*16 + lm)*8];
        acc_s[nf] = __builtin_amdgcn_mfma_f32_16x16x32_bf16(
            aq[ks], bf, acc_s[nf], 0, 0, 0);
      }

    float tmax[4];
    #pragma unroll
    for (int r = 0; r < 4; ++r)
      tmax[r] = fmaxf(fmaxf(acc_s[0][r], acc_s[1][r]),
                      fmaxf(acc_s[2][r], acc_s[3][r]));
    #pragma unroll
    for (int mask = 1; mask < 16; mask <<= 1)
      #pragma unroll
      for (int r = 0; r < 4; ++r)
        tmax[r] = fmaxf(tmax[r], __shfl_xor(tmax[r], mask));
    float alpha[4], rsum[4];
    #pragma unroll
    for (int r = 0; r < 4; ++r){
      float mnew = fmaxf(m_run[r], tmax[r]);
      alpha[r] = __expf(m_run[r] - mnew);
      m_run[r] = mnew;
      rsum[r] = 0.f;
    }
    #pragma unroll
    for (int nf = 0; nf < 4; ++nf)
      #pragma unroll
      for (int r = 0; r < 4; ++r){
        float p = __expf(acc_s[nf][r] - m_run[r]);
        rsum[r] += p;
        Ps[(w*16 + lq*4 + r)*72 + nf*16 + lm] = f2bs(p);
      }
    #pragma unroll
    for (int mask = 1; mask < 16; mask <<= 1)
      #pragma unroll
      for (int r = 0; r < 4; ++r)
        rsum[r] += __shfl_xor(rsum[r], mask);
    #pragma unroll
    for (int r = 0; r < 4; ++r)
      l_run[r] = l_run[r]*alpha[r] + rsum[r];

    #pragma unroll
    for (int nf = 0; nf < 8; ++nf)
      #pragma unroll
      for (int r = 0; r < 4; ++r)
        acc_o[nf][r] *= alpha[r];

    short8 ap[2];
    #pragma unroll
    for (int ks = 0; ks < 2; ++ks)
      ap[ks] = *(const short8*)&Ps[(w*16 + lm)*72 + ks*32 + lq*8];
    #pragma unroll
    for (int ks = 0; ks < 2; ++ks)
      #pragma unroll
      for (int nf = 0; nf < 8; ++nf){
        short8 bv = *(const short8*)&Vts[cur][((ks*4+lq)*128 + nf*16 + lm)*8];
        acc_o[nf] = __builtin_amdgcn_mfma_f32_16x16x32_bf16(
            ap[ks], bv, acc_o[nf], 0, 0, 0);
      }
  }

  float inv[4];
  #pragma unroll
  for (int r = 0; r < 4; ++r) inv[r] = 1.f / l_run[r];
  #pragma unroll
  for (int nf = 0; nf < 8; ++nf)
    #pragma unroll
    for (int r = 0; r < 4; ++r){
      long row = (long)b*1024 + s0 + w*16 + lq*4 + r;
      ctx[row*2048 + h*128 + nf*16 + lm] = f2bs(acc_o[nf][r]*inv[r]);
    }
}

// ---------------------------------------------------------------------------
extern "C" void kernel_launch(void* const* d_in, const int* in_sizes, int n_in,
                              void* d_out, int out_size, void* d_ws, size_t ws_size,
                              hipStream_t stream)
{
  const float* hidden_q = (const float*)d_in[0];   // [2,1024,2048]
  const float* kv_c     = (const float*)d_in[1];   // [2,1024,512]
  const float* Wq       = (const float*)d_in[2];   // [2048,2048]
  const float* w_kc_q   = (const float*)d_in[3];   // [16,128,1536]
  const float* w_kc_kv  = (const float*)d_in[4];   // [16,128,512]
  const float* W_qr     = (const float*)d_in[5];   // [16,1536,64]
  const float* W_kr     = (const float*)d_in[6];   // [16,512,64]
  const float* Wo       = (const float*)d_in[7];   // [2048,2048]
  float* out = (float*)d_out;

  char* wsb = (char*)d_ws;
  size_t off = 0;
  auto take = [&](size_t bytes)->void*{
    void* p = wsb + off; off += (bytes + 255) & ~(size_t)255; return p;
  };
  unsigned short* q_rb  = (unsigned short*)take(4194304);  // [B,H,S,64] bf16
  unsigned short* k_rb  = (unsigned short*)take(4194304);  // [B,H,L,64] bf16
  unsigned short* kv_rb = (unsigned short*)take(2097152);  // [B,L,512] bf16
  float* sink   = (float*)take(2097152);
  float* cosk   = (float*)take(2097152);
  float* sinq   = (float*)take(6291456);
  float* cosq   = (float*)take(6291456);
  unsigned short* q_hk   = (unsigned short*)take(8388608); // [B*S,2048] bf16
  unsigned short* wkcqT  = (unsigned short*)take(6291456); // [16][1536][128] bf16
  unsigned short* WqrT   = (unsigned short*)take(3145728); // [16][64][1536] bf16
  unsigned short* wkckvb = (unsigned short*)take(2097152); // [16][128][512] bf16
  unsigned short* WkrT   = (unsigned short*)take(1048576); // [16][64][512] bf16
  unsigned short* Vt     = (unsigned short*)take(8388608); // [B,H,128,1024] bf16
  char* bigr = (char*)take(100663296);                     // 96 MiB shared region
  unsigned short* hiddenb = (unsigned short*)bigr;              // 8MB (dead after step2)
  unsigned short* Wqb     = (unsigned short*)(bigr + 8388608);  // 8MB (dead after step2)
  unsigned short* q_big   = (unsigned short*)bigr;              // 96MB (steps 3..5)
  unsigned short* Wob     = (unsigned short*)bigr;              // 8MB (after step5)
  unsigned short* ctx_lat = (unsigned short*)(bigr + 8388608);  // 8MB (flash out)

  // tables + 3 converts in one launch
  prep_all<<<13312, 256, 0, stream>>>(sinq, cosq, sink, cosk,
      hidden_q, hiddenb, Wq, Wqb, w_kc_kv, wkckvb);
  transpose_cvt<<<dim3(48,4,16), 256, 0, stream>>>(w_kc_q, wkcqT, 128, 1536, 196608, 196608);
  transpose_cvt<<<dim3(2,48,16), 256, 0, stream>>>(W_qr, WqrT, 1536, 64, 98304, 98304);
  transpose_cvt<<<dim3(2,16,16), 256, 0, stream>>>(W_kr, WkrT, 512, 64, 32768, 32768);

  // 2) q_hk = hidden @ Wq^T   (2048x2048x2048) -> bf16  (64x64 tile, 1024 blocks = 4/CU)
  gemm_mfma<64,64,32,32,unsigned short><<<dim3(32,32,1),256,0,stream>>>(
      hiddenb, Wqb, q_hk, 2048, 2048,2048,2048, 1, 0,0, 0,0, 0,0);

  // 3+4) q_big = RoPE(q_hk @ w_kc_q_T)  fused (per (b,h): 1024x1536x128), 3072 blocks
  gemm_rope<<<dim3(8,12,32),256,0,stream>>>(q_hk, wkcqT, q_big, sinq, cosq);

  // 5) q_r = q_big @ W_qr_T  (per (b,h): 1024x64x1536) -> bf16 (512 blocks)
  gemm_mfma<64,64,32,32,unsigned short><<<dim3(16,1,32),256,0,stream>>>(
      q_big, WqrT, q_rb, 1536, 24576,1536,64, 16,
      25165824,1536, 0,98304, 1048576,65536);

  // Wo convert (aliases dead q_big region — after step 5)
  cvt_bf16<<<4096, 256, 0, stream>>>(Wo, Wob, 1048576);

  // 6) kv_rb = RoPE(kv_c) bf16
  rope_k_kernel<<<2048, 256, 0, stream>>>(kv_c, sink, cosk, kv_rb);

  // 7) k_r = kv_rb @ W_kr_T  (per (b,h): 1024x64x512) -> bf16 (512 blocks)
  gemm_mfma<64,64,32,32,unsigned short><<<dim3(16,1,32),256,0,stream>>>(
      kv_rb, WkrT, k_rb, 512, 512,512,64, 16,
      524288,0, 0,32768, 1048576,65536);

  // 7b) V'^T[b,h][d][l] = w_kc_kv[h] @ kv_rb[b]^T  (per (b,h): 128x1024x512) -> bf16 (512 blocks)
  gemm_mfma<128,64,64,32,unsigned short><<<dim3(1,16,32),256,0,stream>>>(
      wkckvb, kv_rb, Vt, 512, 512,512,1024, 16,
      0,65536, 524288,0, 2097152,131072);

  // 8) MFMA flash attention -> ctx_lat bf16 [b,s][h*128+k]
  flash_mfma<<<dim3(16,16,2),256,0,stream>>>(q_rb, k_rb, Vt, ctx_lat);

  // 10) out = ctx_lat @ Wo^T  (2048x2048x2048) -> fp32 (64x64 tile, 1024 blocks = 4/CU)
  gemm_mfma<64,64,32,32,float><<<dim3(32,32,1),256,0,stream>>>(
      ctx_lat, Wob, out, 2048, 2048,2048,2048, 1, 0,0, 0,0, 0,0);
}

// Round 8
// 387.137 us; speedup vs baseline: 1.1969x; 1.1969x over previous
//
#include <hip/hip_runtime.h>
#include <hip/hip_bf16.h>

// B=2, S=1024, L=1024, DIM_Q=2048, H=16, K=128, D_C=512, D_CQ=1536, R=64

typedef __attribute__((ext_vector_type(8))) short short8;
typedef __attribute__((ext_vector_type(4))) float f32x4;

__device__ __forceinline__ unsigned short f2bs(float v){
  __hip_bfloat16 b = __float2bfloat16(v);
  return *reinterpret_cast<unsigned short*>(&b);
}
__device__ __forceinline__ void storeC(float* p, float v){ *p = v; }
__device__ __forceinline__ void storeC(unsigned short* p, float v){ *p = f2bs(v); }

// async global->LDS, 16B per lane.  LDS dest = wave-uniform base + lane*16.
__device__ __forceinline__ void gl_lds16(const void* g, void* l){
  __builtin_amdgcn_global_load_lds(
      (const __attribute__((address_space(1))) unsigned int*)g,
      (__attribute__((address_space(3))) unsigned int*)l, 16, 0, 0);
}

// ---------------------------------------------------------------------------
// prep_all: packed q-RoPE table (float4: c_lo,s_lo,c_hi,s_hi), k tables,
// and 4 fp32->bf16 converts.  Fast transcendentals (__expf/__sincosf).
// segments: [0,3072) ropeq4 | [3072,4096) k-tables | [4096,8192) hidden |
//           [8192,12288) Wq | [12288,13312) w_kc_kv | [13312,17408) Wo
__global__ __launch_bounds__(256) void prep_all(
    float4* __restrict__ rq,
    float* __restrict__ sink, float* __restrict__ cosk,
    const float* __restrict__ hidden, unsigned short* __restrict__ hiddenb,
    const float* __restrict__ Wq, unsigned short* __restrict__ Wqb,
    const float* __restrict__ wkckv, unsigned short* __restrict__ wkckvb,
    const float* __restrict__ Wo, unsigned short* __restrict__ Wob)
{
  int blk = blockIdx.x;
  if (blk < 3072){
    int idx = blk*256 + threadIdx.x;          // < 1024*768
    int s = idx / 768, j = idx - (idx/768)*768;
    int i1 = j >> 1;                          // freq index (repeat_interleave(2))
    const float cst = -0.011992631f;          // -2*ln(10000)/1536
    float f1 = (float)s * __expf(cst * (float)i1);
    float f2 = (float)s * __expf(cst * (float)(384 + i1));
    float s1, c1, s2, c2;
    __sincosf(f1, &s1, &c1);
    __sincosf(f2, &s2, &c2);
    rq[idx] = make_float4(c1, s1, c2, s2);
    return;
  }
  if (blk < 4096){
    int idx = (blk-3072)*256 + threadIdx.x;   // < 1024*256
    int l = idx >> 8, j = idx & 255;
    const float cst = -0.035977892f;          // -2*ln(10000)/512
    float f = (float)l * __expf(cst * (float)j);
    float sv, cv; __sincosf(f, &sv, &cv);
    int base = l*512 + 2*j;
    sink[base] = sv; sink[base+1] = sv;
    cosk[base] = cv; cosk[base+1] = cv;
    return;
  }
  const float* in; unsigned short* out; int i;
  if (blk < 8192){ in = hidden; out = hiddenb; i = (blk-4096)*256 + threadIdx.x; }
  else if (blk < 12288){ in = Wq; out = Wqb; i = (blk-8192)*256 + threadIdx.x; }
  else if (blk < 13312){ in = wkckv; out = wkckvb; i = (blk-12288)*256 + threadIdx.x; }
  else { in = Wo; out = Wob; i = (blk-13312)*256 + threadIdx.x; }
  float4 v = *(const float4*)(in + (long)i*4);
  ushort4 u; u.x=f2bs(v.x); u.y=f2bs(v.y); u.z=f2bs(v.z); u.w=f2bs(v.w);
  *(ushort4*)(out + (long)i*4) = u;
}

// fp32 [R,Cn] -> bf16 [Cn,R] per batch (32x32 LDS tiles)
__global__ __launch_bounds__(256) void transpose_cvt(
    const float* __restrict__ in, unsigned short* __restrict__ out,
    int R, int Cn, long sIn, long sOut)
{
  __shared__ float tile[32][33];
  const float* ip = in + (long)blockIdx.z*sIn;
  unsigned short* op = out + (long)blockIdx.z*sOut;
  int c0 = blockIdx.x*32, r0 = blockIdx.y*32;
  int tr = threadIdx.x>>5, tc = threadIdx.x&31;
  #pragma unroll
  for (int i=0;i<4;i++)
    tile[tr+i*8][tc] = ip[(long)(r0+tr+i*8)*Cn + c0+tc];
  __syncthreads();
  #pragma unroll
  for (int i=0;i<4;i++)
    op[(long)(c0+tr+i*8)*R + r0+tc] = f2bs(tile[tc][tr+i*8]);
}

// ---------------------------------------------------------------------------
// bf16 MFMA GEMM (NT), double-buffered LDS.  C[m,n] = sum_k A[m,k]*B[n,k].
template<int BM,int BN,int WM,int WN,typename TC>
__global__ __launch_bounds__(256) void gemm_mfma(
    const unsigned short* __restrict__ A, const unsigned short* __restrict__ B,
    TC* __restrict__ C,
    int Kd, int lda, int ldb, int ldc, int Hb,
    long sAb, long sAh, long sBb, long sBh, long sCb, long sCh)
{
  constexpr int MF = WM/16, NF = WN/16;
  constexpr int WGM = BM/WM;
  constexpr int AOPS = (4*BM)/256;
  constexpr int BOPS = (4*BN)/256;

  const int z = blockIdx.z, bb = z/Hb, hh = z - bb*Hb;
  const unsigned short* Ap = A + bb*sAb + hh*sAh;
  const unsigned short* Bp = B + bb*sBb + hh*sBh;
  TC* Cp = C + bb*sCb + hh*sCh;
  const int m0 = blockIdx.x*BM, n0 = blockIdx.y*BN;
  const int t = threadIdx.x, w = t>>6, l = t&63;
  const int wm0 = (w % WGM)*WM, wn0 = (w / WGM)*WN;
  const int lq = l>>4, lm = l&15;

  __shared__ __align__(16) unsigned short As[2][4*BM*8];
  __shared__ __align__(16) unsigned short Bs[2][4*BN*8];

  f32x4 acc[MF][NF];
  #pragma unroll
  for (int mf=0; mf<MF; ++mf)
    #pragma unroll
    for (int nf=0; nf<NF; ++nf)
      acc[mf][nf] = f32x4{0.f,0.f,0.f,0.f};

  auto stage = [&](int buf, int k0){
    #pragma unroll
    for (int o = 0; o < AOPS; ++o){
      int g = o*256 + t;
      int row = g & (BM-1), kq = g / BM;
      gl_lds16(Ap + (long)(m0+row)*lda + k0 + kq*8, &As[buf][(o*256 + w*64)*8]);
    }
    #pragma unroll
    for (int o = 0; o < BOPS; ++o){
      int g = o*256 + t;
      int row = g & (BN-1), kq = g / BN;
      gl_lds16(Bp + (long)(n0+row)*ldb + k0 + kq*8, &Bs[buf][(o*256 + w*64)*8]);
    }
  };

  stage(0, 0);
  const int nIter = Kd >> 5;
  for (int it = 0; it < nIter; ++it){
    const int cur = it & 1;
    __syncthreads();
    if (it+1 < nIter) stage(cur^1, (it+1)*32);
    short8 af[MF], bfr[NF];
    #pragma unroll
    for (int mf=0; mf<MF; ++mf)
      af[mf] = *(const short8*)&As[cur][(lq*BM + wm0 + mf*16 + lm)*8];
    #pragma unroll
    for (int nf=0; nf<NF; ++nf)
      bfr[nf] = *(const short8*)&Bs[cur][(lq*BN + wn0 + nf*16 + lm)*8];
    #pragma unroll
    for (int mf=0; mf<MF; ++mf)
      #pragma unroll
      for (int nf=0; nf<NF; ++nf)
        acc[mf][nf] = __builtin_amdgcn_mfma_f32_16x16x32_bf16(
            af[mf], bfr[nf], acc[mf][nf], 0, 0, 0);
  }

  #pragma unroll
  for (int mf=0; mf<MF; ++mf){
    #pragma unroll
    for (int nf=0; nf<NF; ++nf){
      int row = m0 + wm0 + mf*16 + lq*4;
      int col = n0 + wn0 + nf*16 + lm;
      #pragma unroll
      for (int r=0; r<4; ++r)
        storeC(&Cp[(long)(row+r)*ldc + col], acc[mf][nf][r]);
    }
  }
}

// ---------------------------------------------------------------------------
// q_fused: steps 3+4+5 with NO q_big materialization.
// Per block (b, h, 64 q-rows): q_r[64][64] = sum over 24 chunks of
//   RoPE(q_hk_tile @ W1chunk) @ W2chunk
// Chunk = 64 q_big cols: 32 "lo" (cn*32..+31) + 32 "hi" (+768) so RoPE
// partners live in the same thread's accs (sa[nf] / sa[nf+2]).
// Packed table rq[s][j] = (c_lo,s_lo,c_hi,s_hi).  P goes C->A layout via the
// 72-stride LDS round trip (wave-private rows, no barrier).
__global__ __launch_bounds__(256) void q_fused(
    const unsigned short* __restrict__ A,    // q_hk [2048][2048]
    const unsigned short* __restrict__ W1t,  // wkcqT [16][1536][128]
    const unsigned short* __restrict__ W2t,  // WqrT  [16][64][1536]
    const float4* __restrict__ rq,           // [1024][768]
    unsigned short* __restrict__ qrOut)      // q_rb [B,H,1024,64]
{
  const int z = blockIdx.z, bb = z>>4, hh = z&15;
  const int m0 = blockIdx.x*64;
  const unsigned short* Ap = A + (long)bb*2097152 + hh*128;   // row stride 2048
  const unsigned short* W1 = W1t + (long)hh*196608;           // [1536][128]
  const unsigned short* W2 = W2t + (long)hh*98304;            // [64][1536]
  unsigned short* qo = qrOut + ((long)z*1024 + m0)*64;

  const int t = threadIdx.x, w = t>>6, l = t&63;
  const int lq = l>>4, lm = l&15;

  __shared__ __align__(16) unsigned short As[16*64*8];       // 16 KB
  __shared__ __align__(16) unsigned short W1s[2][16*64*8];   // 2x16 KB
  __shared__ __align__(16) unsigned short W2s[2][8*64*8];    // 2x8 KB
  __shared__ __align__(16) unsigned short Ps[64*72];         // 9 KB

  // stage A tile once: [kq 16][row 64][8]
  #pragma unroll
  for (int o=0;o<4;++o){
    int g=o*256+t; int row=g&63, kq=g>>6;
    gl_lds16(Ap + (long)(m0+row)*2048 + kq*8, &As[(o*256+w*64)*8]);
  }
  auto stageW = [&](int buf, int cn){
    // W1 chunk rows: 0..31 -> lo cols cn*32+row ; 32..63 -> hi cols 736+cn*32+row
    #pragma unroll
    for (int o=0;o<4;++o){
      int g=o*256+t; int row=g&63, kq=g>>6;
      int grow = (row<32) ? (cn*32+row) : (736+cn*32+row);
      gl_lds16(W1 + (long)grow*128 + kq*8, &W1s[buf][(o*256+w*64)*8]);
    }
    // W2 chunk: [kq 8][n 64][8]; k<32 lo, k>=32 hi
    #pragma unroll
    for (int o=0;o<2;++o){
      int g=o*256+t; int n=g&63, kq=g>>6;
      int qk = (kq<4) ? (cn*32+kq*8) : (736+cn*32+kq*8);
      gl_lds16(W2 + (long)n*1536 + qk, &W2s[buf][(o*256+w*64)*8]);
    }
  };
  stageW(0, 0);
  __syncthreads();

  short8 af[4];
  #pragma unroll
  for (int ks=0; ks<4; ++ks)
    af[ks] = *(const short8*)&As[((ks*4+lq)*64 + w*16 + lm)*8];

  f32x4 accr[4];
  #pragma unroll
  for (int nf=0; nf<4; ++nf) accr[nf] = f32x4{0.f,0.f,0.f,0.f};

  for (int cn = 0; cn < 24; ++cn){
    const int cur = cn & 1;
    if (cn < 23) stageW(cur^1, cn+1);

    // S = A @ W1chunk : per wave 16 rows x 64 cols, K=128
    f32x4 sa[4];
    #pragma unroll
    for (int nf=0; nf<4; ++nf) sa[nf] = f32x4{0.f,0.f,0.f,0.f};
    #pragma unroll
    for (int ks=0; ks<4; ++ks)
      #pragma unroll
      for (int nf=0; nf<4; ++nf){
        short8 bf = *(const short8*)&W1s[cur][((ks*4+lq)*64 + nf*16 + lm)*8];
        sa[nf] = __builtin_amdgcn_mfma_f32_16x16x32_bf16(af[ks], bf, sa[nf], 0,0,0);
      }

    // RoPE in registers (pair nf <-> nf+2), write P to LDS (A-layout rows)
    #pragma unroll
    for (int nf=0; nf<2; ++nf)
      #pragma unroll
      for (int r=0; r<4; ++r){
        int srow = m0 + w*16 + lq*4 + r;
        int j = cn*32 + nf*16 + lm;
        float4 rc = rq[(long)srow*768 + j];
        float xl = sa[nf][r], xh = sa[nf+2][r];
        Ps[(w*16 + lq*4 + r)*72 + nf*16 + lm]      = f2bs(xl*rc.x - xh*rc.y);
        Ps[(w*16 + lq*4 + r)*72 + 32 + nf*16 + lm] = f2bs(xh*rc.z + xl*rc.w);
      }

    // accr += P @ W2chunk : K=64
    #pragma unroll
    for (int ks=0; ks<2; ++ks){
      short8 ap = *(const short8*)&Ps[(w*16 + lm)*72 + ks*32 + lq*8];
      #pragma unroll
      for (int nf=0; nf<4; ++nf){
        short8 bw = *(const short8*)&W2s[cur][((ks*4+lq)*64 + nf*16 + lm)*8];
        accr[nf] = __builtin_amdgcn_mfma_f32_16x16x32_bf16(ap, bw, accr[nf], 0,0,0);
      }
    }
    __syncthreads();
  }

  #pragma unroll
  for (int nf=0; nf<4; ++nf)
    #pragma unroll
    for (int r=0; r<4; ++r)
      qo[(long)(w*16 + lq*4 + r)*64 + nf*16 + lm] = f2bs(accr[nf][r]);
}

// ---------------------------------------------------------------------------
// RoPE on kv_c -> kv_rb bf16.  [b,l,512]; pairs (d, d+256).
__global__ __launch_bounds__(256) void rope_k_kernel(
    const float* __restrict__ kc,
    const float* __restrict__ sk, const float* __restrict__ ck,
    unsigned short* __restrict__ kvrb)
{
  int idx = blockIdx.x*256 + threadIdx.x;
  int row = idx >> 8;
  int d = idx & 255;
  int l = row & 1023;
  long base = (long)row*512;
  float xl = kc[base+d], xh = kc[base+d+256];
  int tb = l*512 + d;
  kvrb[base+d]     = f2bs(xl*ck[tb]     - xh*sk[tb]);
  kvrb[base+d+256] = f2bs(xh*ck[tb+256] + xl*sk[tb+256]);
}

// ---------------------------------------------------------------------------
// MFMA flash attention, double-buffered K/V staging.
__global__ __launch_bounds__(256) void flash_mfma(
    const unsigned short* __restrict__ qr, const unsigned short* __restrict__ kr,
    const unsigned short* __restrict__ vt, unsigned short* __restrict__ ctx)
{
  const int b = blockIdx.z, h = blockIdx.y, s0 = blockIdx.x*64;
  const int t = threadIdx.x, w = t>>6, l = t&63;
  const int lq = l>>4, lm = l&15;

  __shared__ __align__(16) unsigned short Qs[8*64*8];
  __shared__ __align__(16) unsigned short Ks[2][8*64*8];
  __shared__ __align__(16) unsigned short Vts[2][8*128*8];
  __shared__ __align__(16) unsigned short Ps[64*72];

  const unsigned short* qbase = qr + ((long)(b*16+h)*1024 + s0)*64;
  const unsigned short* kbase = kr + (long)(b*16+h)*65536;
  const unsigned short* vbase = vt + (long)(b*16+h)*131072;

  auto stageKV = [&](int buf, int l0){
    #pragma unroll
    for (int o = 0; o < 2; ++o){
      int g = o*256 + t;
      int row = g & 63, kq = g >> 6;
      gl_lds16(kbase + (long)(l0+row)*64 + kq*8, &Ks[buf][(o*256 + w*64)*8]);
    }
    #pragma unroll
    for (int o = 0; o < 4; ++o){
      int g = o*256 + t;
      int row = g & 127, kq = g >> 7;
      gl_lds16(vbase + (long)row*1024 + l0 + kq*8, &Vts[buf][(o*256 + w*64)*8]);
    }
  };

  #pragma unroll
  for (int o = 0; o < 2; ++o){
    int g = o*256 + t;
    int row = g & 63, kq = g >> 6;
    gl_lds16(qbase + (long)row*64 + kq*8, &Qs[(o*256 + w*64)*8]);
  }
  stageKV(0, 0);
  __syncthreads();
  short8 aq[2];
  #pragma unroll
  for (int ks = 0; ks < 2; ++ks)
    aq[ks] = *(const short8*)&Qs[((ks*4+lq)*64 + w*16 + lm)*8];

  float m_run[4], l_run[4];
  #pragma unroll
  for (int r = 0; r < 4; ++r){ m_run[r] = -3e38f; l_run[r] = 0.f; }
  f32x4 acc_o[8];
  #pragma unroll
  for (int nf = 0; nf < 8; ++nf) acc_o[nf] = f32x4{0.f,0.f,0.f,0.f};

  for (int it = 0; it < 16; ++it){
    const int cur = it & 1;
    __syncthreads();
    if (it < 15) stageKV(cur^1, (it+1)*64);

    f32x4 acc_s[4];
    #pragma unroll
    for (int nf = 0; nf < 4; ++nf) acc_s[nf] = f32x4{0.f,0.f,0.f,0.f};
    #pragma unroll
    for (int ks = 0; ks < 2; ++ks)
      #pragma unroll
      for (int nf = 0; nf < 4; ++nf){
        short8 bf = *(const short8*)&Ks[cur][((ks*4+lq)*64 + nf*16 + lm)*8];
        acc_s[nf] = __builtin_amdgcn_mfma_f32_16x16x32_bf16(
            aq[ks], bf, acc_s[nf], 0, 0, 0);
      }

    float tmax[4];
    #pragma unroll
    for (int r = 0; r < 4; ++r)
      tmax[r] = fmaxf(fmaxf(acc_s[0][r], acc_s[1][r]),
                      fmaxf(acc_s[2][r], acc_s[3][r]));
    #pragma unroll
    for (int mask = 1; mask < 16; mask <<= 1)
      #pragma unroll
      for (int r = 0; r < 4; ++r)
        tmax[r] = fmaxf(tmax[r], __shfl_xor(tmax[r], mask));
    float alpha[4], rsum[4];
    #pragma unroll
    for (int r = 0; r < 4; ++r){
      float mnew = fmaxf(m_run[r], tmax[r]);
      alpha[r] = __expf(m_run[r] - mnew);
      m_run[r] = mnew;
      rsum[r] = 0.f;
    }
    #pragma unroll
    for (int nf = 0; nf < 4; ++nf)
      #pragma unroll
      for (int r = 0; r < 4; ++r){
        float p = __expf(acc_s[nf][r] - m_run[r]);
        rsum[r] += p;
        Ps[(w*16 + lq*4 + r)*72 + nf*16 + lm] = f2bs(p);
      }
    #pragma unroll
    for (int mask = 1; mask < 16; mask <<= 1)
      #pragma unroll
      for (int r = 0; r < 4; ++r)
        rsum[r] += __shfl_xor(rsum[r], mask);
    #pragma unroll
    for (int r = 0; r < 4; ++r)
      l_run[r] = l_run[r]*alpha[r] + rsum[r];

    #pragma unroll
    for (int nf = 0; nf < 8; ++nf)
      #pragma unroll
      for (int r = 0; r < 4; ++r)
        acc_o[nf][r] *= alpha[r];

    short8 ap[2];
    #pragma unroll
    for (int ks = 0; ks < 2; ++ks)
      ap[ks] = *(const short8*)&Ps[(w*16 + lm)*72 + ks*32 + lq*8];
    #pragma unroll
    for (int ks = 0; ks < 2; ++ks)
      #pragma unroll
      for (int nf = 0; nf < 8; ++nf){
        short8 bv = *(const short8*)&Vts[cur][((ks*4+lq)*128 + nf*16 + lm)*8];
        acc_o[nf] = __builtin_amdgcn_mfma_f32_16x16x32_bf16(
            ap[ks], bv, acc_o[nf], 0, 0, 0);
      }
  }

  float inv[4];
  #pragma unroll
  for (int r = 0; r < 4; ++r) inv[r] = 1.f / l_run[r];
  #pragma unroll
  for (int nf = 0; nf < 8; ++nf)
    #pragma unroll
    for (int r = 0; r < 4; ++r){
      long row = (long)b*1024 + s0 + w*16 + lq*4 + r;
      ctx[row*2048 + h*128 + nf*16 + lm] = f2bs(acc_o[nf][r]*inv[r]);
    }
}

// ---------------------------------------------------------------------------
extern "C" void kernel_launch(void* const* d_in, const int* in_sizes, int n_in,
                              void* d_out, int out_size, void* d_ws, size_t ws_size,
                              hipStream_t stream)
{
  const float* hidden_q = (const float*)d_in[0];   // [2,1024,2048]
  const float* kv_c     = (const float*)d_in[1];   // [2,1024,512]
  const float* Wq       = (const float*)d_in[2];   // [2048,2048]
  const float* w_kc_q   = (const float*)d_in[3];   // [16,128,1536]
  const float* w_kc_kv  = (const float*)d_in[4];   // [16,128,512]
  const float* W_qr     = (const float*)d_in[5];   // [16,1536,64]
  const float* W_kr     = (const float*)d_in[6];   // [16,512,64]
  const float* Wo       = (const float*)d_in[7];   // [2048,2048]
  float* out = (float*)d_out;

  char* wsb = (char*)d_ws;
  size_t off = 0;
  auto take = [&](size_t bytes)->void*{
    void* p = wsb + off; off += (bytes + 255) & ~(size_t)255; return p;
  };
  unsigned short* q_rb  = (unsigned short*)take(4194304);   // [B,H,S,64] bf16
  unsigned short* k_rb  = (unsigned short*)take(4194304);   // [B,H,L,64] bf16
  unsigned short* kv_rb = (unsigned short*)take(2097152);   // [B,L,512] bf16
  float* sink   = (float*)take(2097152);
  float* cosk   = (float*)take(2097152);
  float4* ropeq4 = (float4*)take(12582912);                 // [1024][768] float4
  unsigned short* q_hk   = (unsigned short*)take(8388608);  // [B*S,2048] bf16
  unsigned short* wkcqT  = (unsigned short*)take(6291456);  // [16][1536][128] bf16
  unsigned short* WqrT   = (unsigned short*)take(3145728);  // [16][64][1536] bf16
  unsigned short* wkckvb = (unsigned short*)take(2097152);  // [16][128][512] bf16
  unsigned short* WkrT   = (unsigned short*)take(1048576);  // [16][64][512] bf16
  unsigned short* Vt     = (unsigned short*)take(8388608);  // [B,H,128,1024] bf16
  unsigned short* hiddenb = (unsigned short*)take(8388608); // bf16 hidden
  unsigned short* Wqb     = (unsigned short*)take(8388608); // bf16 Wq
  unsigned short* Wob     = (unsigned short*)take(8388608); // bf16 Wo
  unsigned short* ctx_lat = (unsigned short*)take(8388608); // [B*S,2048] bf16

  // tables + all 4 converts in one launch
  prep_all<<<17408, 256, 0, stream>>>(ropeq4, sink, cosk,
      hidden_q, hiddenb, Wq, Wqb, w_kc_kv, wkckvb, Wo, Wob);
  transpose_cvt<<<dim3(48,4,16), 256, 0, stream>>>(w_kc_q, wkcqT, 128, 1536, 196608, 196608);
  transpose_cvt<<<dim3(2,48,16), 256, 0, stream>>>(W_qr, WqrT, 1536, 64, 98304, 98304);
  transpose_cvt<<<dim3(2,16,16), 256, 0, stream>>>(W_kr, WkrT, 512, 64, 32768, 32768);

  // 2) q_hk = hidden @ Wq^T   (2048x2048x2048) -> bf16  (1024 blocks = 4/CU)
  gemm_mfma<64,64,32,32,unsigned short><<<dim3(32,32,1),256,0,stream>>>(
      hiddenb, Wqb, q_hk, 2048, 2048,2048,2048, 1, 0,0, 0,0, 0,0);

  // 3+4+5) q_r = RoPE(q_hk @ w_kc_q_T) @ W_qr_T, fused — q_big never materialized
  q_fused<<<dim3(16,1,32),256,0,stream>>>(q_hk, wkcqT, WqrT, ropeq4, q_rb);

  // 6) kv_rb = RoPE(kv_c) bf16
  rope_k_kernel<<<2048, 256, 0, stream>>>(kv_c, sink, cosk, kv_rb);

  // 7) k_r = kv_rb @ W_kr_T  (per (b,h): 1024x64x512) -> bf16 (512 blocks)
  gemm_mfma<64,64,32,32,unsigned short><<<dim3(16,1,32),256,0,stream>>>(
      kv_rb, WkrT, k_rb, 512, 512,512,64, 16,
      524288,0, 0,32768, 1048576,65536);

  // 7b) V'^T[b,h][d][l] = w_kc_kv[h] @ kv_rb[b]^T  (per (b,h): 128x1024x512) -> bf16
  gemm_mfma<128,64,64,32,unsigned short><<<dim3(1,16,32),256,0,stream>>>(
      wkckvb, kv_rb, Vt, 512, 512,512,1024, 16,
      0,65536, 524288,0, 2097152,131072);

  // 8) MFMA flash attention -> ctx_lat bf16 [b,s][h*128+k]
  flash_mfma<<<dim3(16,16,2),256,0,stream>>>(q_rb, k_rb, Vt, ctx_lat);

  // 10) out = ctx_lat @ Wo^T  (2048x2048x2048) -> fp32 (1024 blocks = 4/CU)
  gemm_mfma<64,64,32,32,float><<<dim3(32,32,1),256,0,stream>>>(
      ctx_lat, Wob, out, 2048, 2048,2048,2048, 1, 0,0, 0,0, 0,0);
}